// Round 9
// baseline (286.105 us; speedup 1.0000x reference)
//
#include <hip/hip_runtime.h>
#include <hip/hip_bf16.h>
#include <stdint.h>

#define E_ 8
#define H_ 2048
#define I_ 1408
#define T_ 2048
#define K_ 2
#define G_ 128

typedef __bf16 bf16;
typedef bf16 bf16x8 __attribute__((ext_vector_type(8)));
typedef float f32x4 __attribute__((ext_vector_type(4)));

__device__ __forceinline__ uint32_t prm(uint32_t hi, uint32_t lo, uint32_t sel) {
    return __builtin_amdgcn_perm(hi, lo, sel);
}

// Scale-folded dequant tables: bf16(e2m1[m]*s) split into high/low byte LUTs.
struct DequantTab { uint32_t thi0, thi1, tlo0, tlo1; };

__device__ __forceinline__ DequantTab build_tab(float s) {
    union { bf16 h[8]; uint32_t u[4]; } tb;
    tb.h[0] = (bf16)(0.0f);
    tb.h[1] = (bf16)(0.5f * s);
    tb.h[2] = (bf16)(1.0f * s);
    tb.h[3] = (bf16)(1.5f * s);
    tb.h[4] = (bf16)(2.0f * s);
    tb.h[5] = (bf16)(3.0f * s);
    tb.h[6] = (bf16)(4.0f * s);
    tb.h[7] = (bf16)(6.0f * s);
    DequantTab t;
    t.thi0 = prm(tb.u[1], tb.u[0], 0x07050301u);
    t.tlo0 = prm(tb.u[1], tb.u[0], 0x06040200u);
    t.thi1 = prm(tb.u[3], tb.u[2], 0x07050301u);
    t.tlo1 = prm(tb.u[3], tb.u[2], 0x06040200u);
    return t;
}

// 8 fp4 (one u32, k-order) -> 8 scaled bf16 as uint4. ~21 VALU ops.
__device__ __forceinline__ uint4 dequant8t(uint32_t p, const DequantTab& t) {
    const uint32_t pr = p >> 4;
    const uint32_t pe = p  & 0x07070707u;
    const uint32_t po = pr & 0x07070707u;
    const uint32_t He = prm(t.thi1, t.thi0, pe) | ((p  & 0x08080808u) << 4);
    const uint32_t Le = prm(t.tlo1, t.tlo0, pe);
    const uint32_t Ho = prm(t.thi1, t.thi0, po) | ((pr & 0x08080808u) << 4);
    const uint32_t Lo = prm(t.tlo1, t.tlo0, po);
    const uint32_t E01 = prm(He, Le, 0x05010400u);
    const uint32_t E23 = prm(He, Le, 0x07030602u);
    const uint32_t O01 = prm(Ho, Lo, 0x05010400u);
    const uint32_t O23 = prm(Ho, Lo, 0x07030602u);
    return make_uint4(prm(O01, E01, 0x05040100u),
                      prm(O01, E01, 0x07060302u),
                      prm(O23, E23, 0x05040100u),
                      prm(O23, E23, 0x07060302u));
}

// async 16B global -> LDS DMA (wave-uniform-base + lane-linear dest)
__device__ __forceinline__ void gld16(void* lds, const void* g) {
    __builtin_amdgcn_global_load_lds(
        (__attribute__((address_space(1))) void*)g,
        (__attribute__((address_space(3))) void*)lds, 16, 0, 0);
}

#define SB0() __builtin_amdgcn_sched_barrier(0)

// dequant one uint4 (4 u32 = one 64-k row-slice) into swizzled LDS tile WD
#define DQW(WD, PW, TAB) do { \
    uint4 d0_ = dequant8t((PW).x, (TAB)); \
    uint4 d1_ = dequant8t((PW).y, (TAB)); \
    uint4 d2_ = dequant8t((PW).z, (TAB)); \
    uint4 d3_ = dequant8t((PW).w, (TAB)); \
    *(uint4*)&WD[wrow][((cb + 0) ^ rs) * 8] = d0_; \
    *(uint4*)&WD[wrow][((cb + 1) ^ rs) * 8] = d1_; \
    *(uint4*)&WD[wrow][((cb + 2) ^ rs) * 8] = d2_; \
    *(uint4*)&WD[wrow][((cb + 3) ^ rs) * 8] = d3_; \
} while (0)

// ---------------- routing ----------------
__global__ void route_count(const int* __restrict__ topk_idx, int* __restrict__ counts) {
    int p = blockIdx.x * blockDim.x + threadIdx.x;
    if (p < T_ * K_) atomicAdd(&counts[topk_idx[p]], 1);
}

// dense list of 128-row tiles; ntiles stored in offsets[9]
__global__ void route_scan(const int* __restrict__ counts, int* __restrict__ offsets,
                           int* __restrict__ tmap) {
    if (threadIdx.x == 0) {
        int acc = 0, ti = 0;
        for (int e = 0; e < E_; e++) {
            offsets[e] = acc;
            int nt = (counts[e] + 127) >> 7;
            for (int j = 0; j < nt; j++) tmap[ti++] = (e << 16) | j;
            acc += counts[e];
        }
        offsets[E_] = acc;
        offsets[E_ + 1] = ti;            // ntiles
        for (; ti < 64; ti++) tmap[ti] = -1;
    }
}

__global__ void route_fill(const int* __restrict__ topk_idx, const float* __restrict__ topk_w,
                           int* __restrict__ cursors, const int* __restrict__ offsets,
                           int* __restrict__ tok, float* __restrict__ wgt) {
    int p = blockIdx.x * blockDim.x + threadIdx.x;
    if (p < T_ * K_) {
        int e = topk_idx[p];
        int slot = atomicAdd(&cursors[e], 1);
        int idx = offsets[e] + slot;
        tok[idx] = p / K_;
        wgt[idx] = topk_w[p];
    }
}

// x f32 -> bf16
__global__ __launch_bounds__(256)
void xcast_kernel(const float* __restrict__ x, uint4* __restrict__ xb) {
    const int i = blockIdx.x * 256 + threadIdx.x;
    const float4 a = ((const float4*)x)[i * 2];
    const float4 b = ((const float4*)x)[i * 2 + 1];
    union { uint4 u; bf16 h[8]; } r;
    r.h[0] = (bf16)a.x; r.h[1] = (bf16)a.y; r.h[2] = (bf16)a.z; r.h[3] = (bf16)a.w;
    r.h[4] = (bf16)b.x; r.h[5] = (bf16)b.y; r.h[6] = (bf16)b.z; r.h[7] = (bf16)b.w;
    xb[i] = r.u;
}

// ---------------- GEMM1: persistent 768-block grid, 128tok x 64i, BK=64 ----------------
// 48 KB LDS (xs dbuf + SINGLE-buffered weights) -> 3 blocks/CU sustained.
// 2-barrier K-step (R1-verified): dequant -> [vmcnt(6) barrier] -> MFMA ->
// [lgkm barrier]. vmcnt(6) keeps exactly {DMA(t+1)x4, pw(t+1), sc} in flight.
__global__ __launch_bounds__(256, 3)
void gemm1t_kernel(const bf16* __restrict__ xb,
                   const uint32_t* __restrict__ gate_packed,
                   const float* __restrict__ gate_scales,
                   const uint32_t* __restrict__ up_packed,
                   const float* __restrict__ up_scales,
                   const int* __restrict__ offsets,
                   const int* __restrict__ tmap,
                   const int* __restrict__ tok, bf16* __restrict__ h_buf)
{
    __shared__ __align__(16) bf16 xs0[128][64];      // 16 KB
    __shared__ __align__(16) bf16 xs1[128][64];      // 16 KB
    __shared__ __align__(16) bf16 wgs[64][64];       // 8 KB (single-buffered)
    __shared__ __align__(16) bf16 wus[64][64];       // 8 KB -> total 48 KB

    const int tid = threadIdx.x;
    const int ntiles = offsets[E_ + 1];
    const int nwork = ntiles * 22;

    const int xr = tid >> 3;             // 0..31
    const int xc = tid & 7;
    const int xch = (xc ^ (xr & 7)) * 8;

    const int mat  = tid >> 7;           // 0 = gate, 1 = up
    const int id   = tid & 127;
    const int wrow = id >> 1;            // 0..63
    const int quad = id & 1;
    const int cb = quad * 4, rs = wrow & 7;

    const int wave = tid >> 6, lane = tid & 63;
    const int wy = wave >> 1, wx = wave & 1;
    const int lrow = lane & 15, kq = lane >> 4;

    constexpr int NG = H_ / G_;          // 16 kg; 32 K-steps
    constexpr int NT = 2 * NG;

#define MFMA1(XS) do { \
    _Pragma("unroll") \
    for (int kh = 0; kh < 2; ++kh) { \
        bf16x8 a[4], bg[2], bu[2]; \
        _Pragma("unroll") \
        for (int mi = 0; mi < 4; ++mi) { \
            const int ra = wy * 64 + mi * 16 + lrow; \
            a[mi] = *(const bf16x8*)&XS[ra][((kh * 4 + kq) ^ (ra & 7)) * 8]; \
        } \
        _Pragma("unroll") \
        for (int ni = 0; ni < 2; ++ni) { \
            const int rbq = wx * 32 + ni * 16 + lrow; \
            const int cbq = ((kh * 4 + kq) ^ (rbq & 7)) * 8; \
            bg[ni] = *(const bf16x8*)&wgs[rbq][cbq]; \
            bu[ni] = *(const bf16x8*)&wus[rbq][cbq]; \
        } \
        _Pragma("unroll") \
        for (int mi = 0; mi < 4; ++mi) \
            _Pragma("unroll") \
            for (int ni = 0; ni < 2; ++ni) { \
                accg[mi][ni] = __builtin_amdgcn_mfma_f32_16x16x32_bf16(a[mi], bg[ni], accg[mi][ni], 0, 0, 0); \
                accu[mi][ni] = __builtin_amdgcn_mfma_f32_16x16x32_bf16(a[mi], bu[ni], accu[mi][ni], 0, 0, 0); \
            } \
    } \
} while (0)

    for (int wk = blockIdx.x; wk < nwork; wk += gridDim.x) {
        const int wt = wk / 22;
        const int itile = wk - wt * 22;              // 0..21 (64 i-cols)
        const int tm = tmap[wt];
        const int e = tm >> 16, ty = tm & 0xffff;    // 128-token tile
        const int row0 = offsets[e];
        const int cnt = offsets[e + 1] - row0;

        // --- x staging roles: 4 gld16/thread/step, swizzled source chunk ---
        const bf16* xsrc[4];
        bf16 *xdst0[4], *xdst1[4];
#pragma unroll
        for (int j = 0; j < 4; ++j) {
            int g = ty * 128 + xr + j * 32;
            g = (g < cnt) ? g : (cnt - 1);
            xsrc[j] = xb + (size_t)tok[row0 + g] * H_ + xch;
            xdst0[j] = &xs0[xr + j * 32][xc * 8];
            xdst1[j] = &xs1[xr + j * 32][xc * 8];
        }

        // --- weight roles ---
        const int irow = itile * 64 + wrow;
        const uint32_t* wp_row = (mat ? up_packed : gate_packed)
            + (size_t)e * I_ * (H_ / 8) + (size_t)irow * (H_ / 8) + quad * 4;
        const float* ws_row = (mat ? up_scales : gate_scales)
            + (size_t)e * (H_ / G_) * I_ + irow;
        bf16 (* const wd)[64] = mat ? wus : wgs;

        f32x4 accg[4][2] = {};
        f32x4 accu[4][2] = {};

        // prologue: DMA(0) -> xs0, pw(0), sc(0)   (order pinned: DMA before pw)
#pragma unroll
        for (int j = 0; j < 4; ++j) gld16(xdst0[j], xsrc[j]);
        SB0();
        uint4 pw = *(const uint4*)(wp_row);
        float sc = ws_row[0];
        SB0();

        float scn = sc;
        uint4 pwn;
        for (int kg = 0; kg < NG; ++kg) {
            const DequantTab tab = build_tab(sc);    // waits sc(kg): drains all older VMEM
#pragma unroll
            for (int kh2 = 0; kh2 < 2; ++kh2) {
                const int t = kg * 2 + kh2;
                const bool lastT = (t == NT - 1);
                // stage issues for t+1: DMA first, then pw (so dequant's pw(t)
                // wait provably drains DMA(t)), then sc at even steps.
                if (!lastT) {
                    bf16* const* xd = kh2 ? xdst0 : xdst1;
#pragma unroll
                    for (int j = 0; j < 4; ++j) gld16(xd[j], xsrc[j] + (t + 1) * 64);
                    SB0();
                    pwn = *(const uint4*)(wp_row + (size_t)(t + 1) * 8);
                    if (kh2 == 0) {
                        const int kgn = (kg + 1 < NG) ? kg + 1 : kg;
                        scn = ws_row[(size_t)kgn * I_];
                    }
                    SB0();
                }
                // dequant(t) -> single-buffered weight LDS
                DQW(wd, pw, tab);
                SB0();
                if (!lastT) asm volatile("s_waitcnt vmcnt(6) lgkmcnt(0)" ::: "memory");
                else        asm volatile("s_waitcnt vmcnt(0) lgkmcnt(0)" ::: "memory");
                __builtin_amdgcn_s_barrier();
                SB0();
                if (kh2 == 0) MFMA1(xs0); else MFMA1(xs1);
                SB0();
                asm volatile("s_waitcnt lgkmcnt(0)" ::: "memory");
                __builtin_amdgcn_s_barrier();
                SB0();
                pw = pwn;
            }
            sc = scn;
        }

        // epilogue: h = silu(g)*u. C layout: col=lane&15, row=(lane>>4)*4+r
#pragma unroll
        for (int mi = 0; mi < 4; ++mi)
#pragma unroll
            for (int ni = 0; ni < 2; ++ni) {
                const int icol = itile * 64 + wx * 32 + ni * 16 + lrow;
#pragma unroll
                for (int r = 0; r < 4; ++r) {
                    const int grow = ty * 128 + wy * 64 + mi * 16 + kq * 4 + r;
                    if (grow < cnt) {
                        const float gv = accg[mi][ni][r];
                        const float hv = gv / (1.f + __expf(-gv)) * accu[mi][ni][r];
                        h_buf[(size_t)(row0 + grow) * I_ + icol] = (bf16)hv;
                    }
                }
            }
    }
#undef MFMA1
}

// ---------------- GEMM2: persistent 768-block grid, 128tok x 128h, fused combine ----------------
__global__ __launch_bounds__(256, 3)
void gemm2t_kernel(const bf16* __restrict__ h_buf,
                   const uint32_t* __restrict__ down_packed,
                   const float* __restrict__ down_scales,
                   const int* __restrict__ offsets,
                   const int* __restrict__ tmap,
                   const int* __restrict__ tok,
                   const float* __restrict__ wgt, float* __restrict__ out)
{
    __shared__ __align__(16) bf16 hs0[128][64];      // 16 KB
    __shared__ __align__(16) bf16 hs1[128][64];      // 16 KB
    __shared__ __align__(16) bf16 wds[128][64];      // 16 KB (single) -> 48 KB

    const int tid = threadIdx.x;
    const int ntiles = offsets[E_ + 1];
    const int nwork = ntiles * 16;

    const int xr = tid >> 3;
    const int xc = tid & 7;
    const int xch = (xc ^ (xr & 7)) * 8;

    const int wrow = tid >> 1;           // 0..127
    const int quad = tid & 1;
    const int cb = quad * 4, rs = wrow & 7;

    const int wave = tid >> 6, lane = tid & 63;
    const int wy = wave >> 1, wx = wave & 1;
    const int lrow = lane & 15, kq = lane >> 4;

    constexpr int NG = I_ / G_;          // 11 kg; 22 K-steps
    constexpr int NT = 2 * NG;

#define MFMA2(HS) do { \
    _Pragma("unroll") \
    for (int kh = 0; kh < 2; ++kh) { \
        bf16x8 a[4], b[4]; \
        _Pragma("unroll") \
        for (int mi = 0; mi < 4; ++mi) { \
            const int ra = wy * 64 + mi * 16 + lrow; \
            a[mi] = *(const bf16x8*)&HS[ra][((kh * 4 + kq) ^ (ra & 7)) * 8]; \
        } \
        _Pragma("unroll") \
        for (int ni = 0; ni < 4; ++ni) { \
            const int rbq = wx * 64 + ni * 16 + lrow; \
            b[ni] = *(const bf16x8*)&wds[rbq][((kh * 4 + kq) ^ (rbq & 7)) * 8]; \
        } \
        _Pragma("unroll") \
        for (int mi = 0; mi < 4; ++mi) \
            _Pragma("unroll") \
            for (int ni = 0; ni < 4; ++ni) \
                acc[mi][ni] = __builtin_amdgcn_mfma_f32_16x16x32_bf16(a[mi], b[ni], acc[mi][ni], 0, 0, 0); \
    } \
} while (0)

    for (int wk = blockIdx.x; wk < nwork; wk += gridDim.x) {
        const int wt = wk >> 4;
        const int htile = wk & 15;                   // 128 h-cols
        const int tm = tmap[wt];
        const int e = tm >> 16, ty = tm & 0xffff;
        const int row0 = offsets[e];
        const int cnt = offsets[e + 1] - row0;

        const bf16* hsrc[4];
        bf16 *hdst0[4], *hdst1[4];
#pragma unroll
        for (int j = 0; j < 4; ++j) {
            int g = ty * 128 + xr + j * 32;
            g = (g < cnt) ? g : (cnt - 1);
            hsrc[j] = h_buf + (size_t)(row0 + g) * I_ + xch;
            hdst0[j] = &hs0[xr + j * 32][xc * 8];
            hdst1[j] = &hs1[xr + j * 32][xc * 8];
        }

        const int hrow = htile * 128 + wrow;
        const uint32_t* dp_row = down_packed + (size_t)e * H_ * (I_ / 8) + (size_t)hrow * (I_ / 8) + quad * 4;
        const float* ds_row = down_scales + (size_t)e * (I_ / G_) * H_ + hrow;

        f32x4 acc[4][4] = {};

        // prologue: DMA(0) -> hs0, pw(0), sc(0)
#pragma unroll
        for (int j = 0; j < 4; ++j) gld16(hdst0[j], hsrc[j]);
        SB0();
        uint4 pw = *(const uint4*)(dp_row);
        float sc = ds_row[0];
        SB0();

        float scn = sc;
        uint4 pwn;
        for (int kg = 0; kg < NG; ++kg) {
            const DequantTab tab = build_tab(sc);
#pragma unroll
            for (int kh2 = 0; kh2 < 2; ++kh2) {
                const int t = kg * 2 + kh2;
                const bool lastT = (t == NT - 1);
                if (!lastT) {
                    bf16* const* hd = kh2 ? hdst0 : hdst1;
#pragma unroll
                    for (int j = 0; j < 4; ++j) gld16(hd[j], hsrc[j] + (t + 1) * 64);
                    SB0();
                    pwn = *(const uint4*)(dp_row + (size_t)(t + 1) * 8);
                    if (kh2 == 0) {
                        const int kgn = (kg + 1 < NG) ? kg + 1 : kg;
                        scn = ds_row[(size_t)kgn * H_];
                    }
                    SB0();
                }
                DQW(wds, pw, tab);
                SB0();
                if (!lastT) asm volatile("s_waitcnt vmcnt(6) lgkmcnt(0)" ::: "memory");
                else        asm volatile("s_waitcnt vmcnt(0) lgkmcnt(0)" ::: "memory");
                __builtin_amdgcn_s_barrier();
                SB0();
                if (kh2 == 0) MFMA2(hs0); else MFMA2(hs1);
                SB0();
                asm volatile("s_waitcnt lgkmcnt(0)" ::: "memory");
                __builtin_amdgcn_s_barrier();
                SB0();
                pw = pwn;
            }
            sc = scn;
        }

        // epilogue: fused combine — each out element gets exactly K_=2 atomic adds
#pragma unroll
        for (int mi = 0; mi < 4; ++mi)
#pragma unroll
            for (int r = 0; r < 4; ++r) {
                const int grow = ty * 128 + wy * 64 + mi * 16 + kq * 4 + r;
                if (grow < cnt) {
                    const int slot = row0 + grow;
                    const float w = wgt[slot];
                    const int tk = tok[slot];
#pragma unroll
                    for (int ni = 0; ni < 4; ++ni) {
                        const int col = htile * 128 + wx * 64 + ni * 16 + lrow;
                        atomicAdd(out + (size_t)tk * H_ + col, acc[mi][ni][r] * w);
                    }
                }
            }
    }
#undef MFMA2
}

extern "C" void kernel_launch(void* const* d_in, const int* in_sizes, int n_in,
                              void* d_out, int out_size, void* d_ws, size_t ws_size,
                              hipStream_t stream) {
    const float* x = (const float*)d_in[0];
    const uint32_t* gate_packed = (const uint32_t*)d_in[1];
    const float* gate_scales = (const float*)d_in[2];
    const uint32_t* up_packed = (const uint32_t*)d_in[3];
    const float* up_scales = (const float*)d_in[4];
    const uint32_t* down_packed = (const uint32_t*)d_in[5];
    const float* down_scales = (const float*)d_in[6];
    const int* topk_idx = (const int*)d_in[7];
    const float* topk_w = (const float*)d_in[8];
    float* out = (float*)d_out;

    // workspace layout (bytes)
    char* ws = (char*)d_ws;
    int* counts  = (int*)ws;              // 32
    int* cursors = (int*)(ws + 32);       // 32
    int* offsets = (int*)(ws + 64);       // 64 (offsets[9] = ntiles)
    int* tmap    = (int*)(ws + 128);      // 256 (64 ints)
    int* tok     = (int*)(ws + 640);      // 16384
    float* wgt   = (float*)(ws + 17024);  // 16384
    bf16* h_buf  = (bf16*)(ws + 49792);   // 11,534,336
    bf16* xb     = (bf16*)(ws + 49792 + 11534336ull);                 // 8,388,608

    hipMemsetAsync(d_ws, 0, 1024, stream);
    hipMemsetAsync(d_out, 0, out_size, stream);

    route_count<<<(T_ * K_ + 255) / 256, 256, 0, stream>>>(topk_idx, counts);
    route_scan<<<1, 64, 0, stream>>>(counts, offsets, tmap);
    route_fill<<<(T_ * K_ + 255) / 256, 256, 0, stream>>>(topk_idx, topk_w, cursors, offsets,
                                                          tok, wgt);
    xcast_kernel<<<T_ * H_ / 8 / 256, 256, 0, stream>>>(x, (uint4*)xb);

    // persistent grids: 768 blocks = 3 blocks/CU x 256 CU (48 KB LDS each)
    gemm1t_kernel<<<768, 256, 0, stream>>>(xb, gate_packed, gate_scales, up_packed, up_scales,
                                           offsets, tmap, tok, h_buf);
    gemm2t_kernel<<<768, 256, 0, stream>>>(h_buf, down_packed, down_scales,
                                           offsets, tmap, tok, wgt, out);
}